// Round 2
// baseline (5247.066 us; speedup 1.0000x reference)
//
#include <hip/hip_runtime.h>
#include <hip/hip_bf16.h>
#include <cstdint>

#define B_ 256
#define D_ 128
#define T_ 512
#define H_ 256
#define C_ 10

#define SENT 0xFFFFFFFFFFFFFFFFull

using f32x4 = __attribute__((ext_vector_type(4))) float;
using s16x8 = __attribute__((ext_vector_type(8))) short;

__device__ __forceinline__ unsigned short f2bf(float f) {
    union { float f; uint32_t u; } a; a.f = f;
    uint32_t u = a.u;
    uint32_t r = (u + 0x7fffu + ((u >> 16) & 1u)) >> 16;   // RNE
    return (unsigned short)r;
}

__device__ __forceinline__ float sigm(float v) { return 1.0f / (1.0f + __expf(-v)); }

// Raw workgroup barrier: per-wave LDS drain only. Unlike __syncthreads(), does
// NOT emit s_waitcnt vmcnt(0) -> our early-issued h loads stay in flight.
__device__ __forceinline__ void lds_barrier() {
    asm volatile("s_waitcnt lgkmcnt(0)" ::: "memory");
    __builtin_amdgcn_sched_barrier(0);
    __builtin_amdgcn_s_barrier();
    __builtin_amdgcn_sched_barrier(0);
}

// ---------------------------------------------------------------------------
// Kernel 1: transpose x [B][D][T] f32  ->  xt [T][B][D] bf16
// ---------------------------------------------------------------------------
__global__ void xt_kernel(const float* __restrict__ x, unsigned short* __restrict__ xt) {
    __shared__ unsigned short tile[128][66];
    const int b  = blockIdx.x >> 3;
    const int t0 = (blockIdx.x & 7) << 6;
    const int tid = threadIdx.x;
    const int j  = tid & 63;
    const int dq = tid >> 6;

#pragma unroll
    for (int it = 0; it < 32; ++it) {
        int d = it * 4 + dq;
        tile[d][j] = f2bf(x[(size_t)(b * D_ + d) * T_ + t0 + j]);
    }
    __syncthreads();

    uint32_t* xt32 = (uint32_t*)xt;
#pragma unroll
    for (int it = 0; it < 16; ++it) {
        int tl = it * 4 + dq;
        int dp = j;
        uint32_t lo = tile[2 * dp][tl];
        uint32_t hi = tile[2 * dp + 1][tl];
        xt32[(size_t)((t0 + tl) * B_ + b) * (D_ / 2) + dp] = lo | (hi << 16);
    }
}

// ---------------------------------------------------------------------------
// Kernel 2: persistent LSTM recurrence.
// 256 blocks = 16 batch-chunks (bc) x 16 H-slices (hc), 256 threads (4 waves).
// h exchange is intra-clique only (same bc). Cliques are blockIdx = bc (mod 16)
// -> all = bc (mod 8) -> land on ONE XCD under round-robin dispatch. We verify
// this at runtime via HW_REG_XCC_ID; if the clique shares an XCD, the exchange
// uses sc0 (L1-bypass, serviced at the SHARED coherent L2, ~200cy RT) instead
// of agent-scope atomics (sc1, MALL, ~700cy RT). Fallback to the agent path if
// placement isn't uniform. Data words are self-validating (0xFF sentinel =
// bf16 NaN, unreachable for tanh*sigmoid outputs) -> no flags, no fences.
// In-loop barriers are lgkm-only (no vmcnt drain), so the h loads issued at
// the end of step t are still in flight when step t+1's poll first checks.
// ---------------------------------------------------------------------------
__global__ void __launch_bounds__(256) lstm_kernel(
    const float* __restrict__ Wgx, const float* __restrict__ Wix,
    const float* __restrict__ Wfx, const float* __restrict__ Wox,
    const float* __restrict__ Wgh, const float* __restrict__ Wih,
    const float* __restrict__ Wfh, const float* __restrict__ Woh,
    const float* __restrict__ bg,  const float* __restrict__ bi,
    const float* __restrict__ bf2, const float* __restrict__ bo,
    const unsigned short* __restrict__ xt,
    uint64_t* __restrict__ hbuf,
    int* __restrict__ xcds,
    float* __restrict__ hfin)
{
    __shared__ __align__(16) unsigned short Wh_s[4][16][264];
    __shared__ __align__(16) unsigned short Wx_s[4][16][136];
    __shared__ __align__(16) unsigned short h_s[16][264];
    __shared__ __align__(16) unsigned short x_s[2][16][136];
    __shared__ float pre_s[4][16][17];
    __shared__ float bias_s[4][16];
    __shared__ int use_l2_s;

    const int tid  = threadIdx.x;
    const int bc   = blockIdx.x & 15;
    const int hc   = blockIdx.x >> 4;
    const int wave = tid >> 6;
    const int lane = tid & 63;
    const int mrow = lane & 15;
    const int quad = lane >> 4;

    // publish my XCD id early so the MALL round trips overlap weight staging
    if (tid == 0) {
        int xcc = (int)(__builtin_amdgcn_s_getreg((3 << 11) | 20) & 0xF); // HW_REG_XCC_ID[3:0]
        __hip_atomic_store(&xcds[blockIdx.x], xcc, __ATOMIC_RELAXED,
                           __HIP_MEMORY_SCOPE_AGENT);
    }

    const float* Wh[4] = {Wgh, Wih, Wfh, Woh};
    const float* Wx[4] = {Wgx, Wix, Wfx, Wox};
    const float* bias[4] = {bg, bi, bf2, bo};

#pragma unroll
    for (int g = 0; g < 4; ++g) {
        for (int it = 0; it < 16; ++it) {
            int idx = it * 256 + tid;
            int k = idx >> 4, c = idx & 15;
            Wh_s[g][c][k] = f2bf(Wh[g][(size_t)k * H_ + hc * 16 + c]);
        }
        for (int it = 0; it < 8; ++it) {
            int idx = it * 256 + tid;
            int k = idx >> 4, c = idx & 15;
            Wx_s[g][c][k] = f2bf(Wx[g][(size_t)k * H_ + hc * 16 + c]);
        }
    }
    if (tid < 64) bias_s[tid >> 4][tid & 15] = bias[tid >> 4][hc * 16 + (tid & 15)];

    // clique XCD-uniformity check: my 16 mates are blocks {bc + 16*k}
    if (wave == 0) {
        int v;
        const int mate = bc + 16 * (lane & 15);
        do {
            v = __hip_atomic_load(&xcds[mate], __ATOMIC_RELAXED, __HIP_MEMORY_SCOPE_AGENT);
        } while (v < 0);
        int v0 = __shfl(v, 0, 64);
        unsigned long long mm = __ballot(v == v0);
        if (lane == 0) use_l2_s = (mm == ~0ull) ? 1 : 0;
    }
    __syncthreads();

    const bool use_l2 = (use_l2_s != 0);

    // hoist this wave's loop-invariant weight fragments to registers
    s16x8 wxf[4], whf[8];
#pragma unroll
    for (int kk = 0; kk < 4; ++kk)
        wxf[kk] = *(const s16x8*)&Wx_s[wave][mrow][kk * 32 + quad * 8];
#pragma unroll
    for (int kk = 0; kk < 8; ++kk)
        whf[kk] = *(const s16x8*)&Wh_s[wave][mrow][kk * 32 + quad * 8];

    const int b_l = tid >> 4;
    const int u_l = tid & 15;
    float c_st = 0.0f, h_st = 0.0f;

    uint64_t hv[4] = {SENT, SENT, SENT, SENT};

    // publish x for t=0 (x_s is double-buffered; buffer t&1 read at step t)
    uint4 xvn = *(const uint4*)(xt + ((size_t)(0 * B_ + bc * 16 + b_l) * D_ + u_l * 8));
    *(uint4*)&x_s[0][b_l][u_l * 8] = xvn;

    for (int t = 0; t < T_; ++t) {
        if (t > 0) {
            const uint64_t* src = hbuf + (size_t)(t - 1) * (B_ * (H_ / 4));
            if (use_l2) {
                // L2-local poll: wait in-flight loads, check, re-issue sc0 loads
                int spins = 0;
                for (;;) {
                    asm volatile("s_waitcnt vmcnt(0)" ::: "memory");
                    __builtin_amdgcn_sched_barrier(0);
                    bool ok = (hv[0] != SENT) && (hv[1] != SENT) &&
                              (hv[2] != SENT) && (hv[3] != SENT);
                    if (__all(ok)) break;
                    if (++spins <= 64) {
#pragma unroll
                        for (int i = 0; i < 4; ++i)
                            asm volatile("global_load_dwordx2 %0, %1, off sc0"
                                         : "=v"(hv[i])
                                         : "v"(src + (size_t)(bc * 16 + i * 4 + wave) * (H_ / 4) + lane));
                    } else {
                        // safety net: placement assumption violated -> MALL copy
                        __builtin_amdgcn_s_sleep(2);
#pragma unroll
                        for (int i = 0; i < 4; ++i)
                            if (hv[i] == SENT)
                                hv[i] = __hip_atomic_load(
                                    src + (size_t)(bc * 16 + i * 4 + wave) * (H_ / 4) + lane,
                                    __ATOMIC_RELAXED, __HIP_MEMORY_SCOPE_AGENT);
                    }
                }
            } else {
                for (;;) {
                    bool ok = true;
#pragma unroll
                    for (int i = 0; i < 4; ++i) ok &= (hv[i] != SENT);
                    if (ok) break;
                    __builtin_amdgcn_s_sleep(1);
#pragma unroll
                    for (int i = 0; i < 4; ++i)
                        if (hv[i] == SENT)
                            hv[i] = __hip_atomic_load(
                                src + (size_t)(bc * 16 + i * 4 + wave) * (H_ / 4) + lane,
                                __ATOMIC_RELAXED, __HIP_MEMORY_SCOPE_AGENT);
                }
            }
#pragma unroll
            for (int i = 0; i < 4; ++i)
                *(uint64_t*)&h_s[i * 4 + wave][lane * 4] = hv[i];
        }

        // xt prefetch AFTER the poll so the poll's vmcnt(0) never stalls on it;
        // its HBM latency hides under the MFMA + activation phases below.
        uint4 xv_next;
        if (t + 1 < T_)
            xv_next = *(const uint4*)(xt + ((size_t)((t + 1) * B_ + bc * 16 + b_l) * D_ + u_l * 8));

        lds_barrier();   // B: h_s (and x_s published last iter) visible

        f32x4 accx = {0.f, 0.f, 0.f, 0.f};
#pragma unroll
        for (int kk = 0; kk < 4; ++kk) {
            s16x8 a = *(const s16x8*)&x_s[t & 1][mrow][kk * 32 + quad * 8];
            accx = __builtin_amdgcn_mfma_f32_16x16x32_bf16(a, wxf[kk], accx, 0, 0, 0);
        }

        f32x4 acc0 = {0.f, 0.f, 0.f, 0.f};
        f32x4 acc1 = {0.f, 0.f, 0.f, 0.f};
        if (t > 0) {
#pragma unroll
            for (int j = 0; j < 4; ++j) {
                s16x8 a  = *(const s16x8*)&h_s[mrow][(2 * j) * 32 + quad * 8];
                acc0 = __builtin_amdgcn_mfma_f32_16x16x32_bf16(a, whf[2 * j], acc0, 0, 0, 0);
                s16x8 a2 = *(const s16x8*)&h_s[mrow][(2 * j + 1) * 32 + quad * 8];
                acc1 = __builtin_amdgcn_mfma_f32_16x16x32_bf16(a2, whf[2 * j + 1], acc1, 0, 0, 0);
            }
        }

#pragma unroll
        for (int r = 0; r < 4; ++r)
            pre_s[wave][quad * 4 + r][mrow] = accx[r] + acc0[r] + acc1[r];
        lds_barrier();   // C: pre-activations ready

        float pg = pre_s[0][b_l][u_l] + bias_s[0][u_l];
        float pi = pre_s[1][b_l][u_l] + bias_s[1][u_l];
        float pf = pre_s[2][b_l][u_l] + bias_s[2][u_l];
        float po = pre_s[3][b_l][u_l] + bias_s[3][u_l];
        float gg = 2.0f * sigm(2.0f * pg) - 1.0f;   // tanh
        float ii = sigm(pi), ff = sigm(pf), oo = sigm(po);
        c_st = gg * ii + c_st * ff;
        float th = 2.0f * sigm(2.0f * c_st) - 1.0f; // tanh(c)
        h_st = th * oo;

        // pack 4 units into a u64 and publish (fire-and-forget, self-validating)
        uint32_t hb = f2bf(h_st);
        uint32_t p = hb | ((uint32_t)__shfl_down((int)hb, 1, 64) << 16);
        uint32_t q = (uint32_t)__shfl_down((int)p, 2, 64);
        if ((tid & 3) == 0) {
            uint64_t val = ((uint64_t)q << 32) | (uint64_t)p;
            uint64_t* dst = hbuf + (size_t)t * (B_ * (H_ / 4)) +
                            (size_t)(bc * 16 + b_l) * (H_ / 4) + hc * 4 + (u_l >> 2);
            if (use_l2) {
                // L2-visible store for clique mates...
                asm volatile("global_store_dwordx2 %0, %1, off sc0"
                             :: "v"(dst), "v"(val) : "memory");
                // ...plus MALL copy so the spin-cap fallback can always recover
                __hip_atomic_store(dst, val, __ATOMIC_RELAXED, __HIP_MEMORY_SCOPE_AGENT);
            } else {
                __hip_atomic_store(dst, val, __ATOMIC_RELAXED, __HIP_MEMORY_SCOPE_AGENT);
            }
        }

        // early-issue next step's h loads (stay in flight across the raw barriers)
        if (t + 1 < T_) {
            const uint64_t* nsrc = hbuf + (size_t)t * (B_ * (H_ / 4));
            if (use_l2) {
#pragma unroll
                for (int i = 0; i < 4; ++i)
                    asm volatile("global_load_dwordx2 %0, %1, off sc0"
                                 : "=v"(hv[i])
                                 : "v"(nsrc + (size_t)(bc * 16 + i * 4 + wave) * (H_ / 4) + lane));
            } else {
#pragma unroll
                for (int i = 0; i < 4; ++i)
                    hv[i] = __hip_atomic_load(
                        nsrc + (size_t)(bc * 16 + i * 4 + wave) * (H_ / 4) + lane,
                        __ATOMIC_RELAXED, __HIP_MEMORY_SCOPE_AGENT);
            }
            // publish x for step t+1 into the other buffer (ordered by barrier B)
            *(uint4*)&x_s[(t + 1) & 1][b_l][u_l * 8] = xv_next;
        }
    }

    hfin[(size_t)(bc * 16 + b_l) * H_ + hc * 16 + u_l] = h_st;
}

// ---------------------------------------------------------------------------
// Kernel 3: out = h_final @ W_ph + b_p
// ---------------------------------------------------------------------------
__global__ void proj_kernel(const float* __restrict__ hfin, const float* __restrict__ Wph,
                            const float* __restrict__ bp, float* __restrict__ out) {
    int gid = blockIdx.x * 256 + threadIdx.x;
    if (gid >= B_ * C_) return;
    int b = gid / C_, cc = gid % C_;
    float acc = bp[cc];
#pragma unroll 8
    for (int u = 0; u < H_; ++u)
        acc += hfin[(size_t)b * H_ + u] * Wph[(size_t)u * C_ + cc];
    out[gid] = acc;
}

// ---------------------------------------------------------------------------
extern "C" void kernel_launch(void* const* d_in, const int* in_sizes, int n_in,
                              void* d_out, int out_size, void* d_ws, size_t ws_size,
                              hipStream_t stream) {
    const float* x   = (const float*)d_in[0];
    const float* Wgx = (const float*)d_in[1];
    const float* Wix = (const float*)d_in[2];
    const float* Wfx = (const float*)d_in[3];
    const float* Wox = (const float*)d_in[4];
    const float* Wgh = (const float*)d_in[5];
    const float* Wih = (const float*)d_in[6];
    const float* Wfh = (const float*)d_in[7];
    const float* Woh = (const float*)d_in[8];
    const float* bg  = (const float*)d_in[9];
    const float* bi  = (const float*)d_in[10];
    const float* bf2 = (const float*)d_in[11];
    const float* bo  = (const float*)d_in[12];
    const float* Wph = (const float*)d_in[13];
    const float* bp  = (const float*)d_in[14];

    const size_t hbuf_bytes = (size_t)T_ * B_ * (H_ / 4) * sizeof(uint64_t); // 64 MB

    char* ws = (char*)d_ws;
    int*            xcds = (int*)ws;                         // 1024 B
    uint64_t*       hbuf = (uint64_t*)(ws + 1024);
    float*          hfin = (float*)(ws + 1024 + hbuf_bytes);
    unsigned short* xt   = (unsigned short*)(ws + 1024 + hbuf_bytes +
                                             (size_t)B_ * H_ * sizeof(float));

    // 0xFF fills: xcds -> -1 (unwritten), hbuf -> bf16 NaN sentinel
    hipMemsetAsync(ws, 0xFF, 1024 + hbuf_bytes, stream);

    xt_kernel<<<B_ * (T_ / 64), 256, 0, stream>>>(x, xt);

    lstm_kernel<<<256, 256, 0, stream>>>(Wgx, Wix, Wfx, Wox, Wgh, Wih, Wfh, Woh,
                                         bg, bi, bf2, bo, xt, hbuf, xcds, hfin);

    proj_kernel<<<(B_ * C_ + 255) / 256, 256, 0, stream>>>(hfin, Wph, bp, (float*)d_out);
}

// Round 3
// 2231.013 us; speedup vs baseline: 2.3519x; 2.3519x over previous
//
#include <hip/hip_runtime.h>
#include <hip/hip_bf16.h>
#include <cstdint>

#define B_ 256
#define D_ 128
#define T_ 512
#define H_ 256
#define C_ 10
#define S32 0xFFFFFFFFu

using f32x4 = __attribute__((ext_vector_type(4))) float;
using s16x8 = __attribute__((ext_vector_type(8))) short;
using u32x4 = __attribute__((ext_vector_type(4))) unsigned int;

__device__ __forceinline__ unsigned short f2bf(float f) {
    union { float f; uint32_t u; } a; a.f = f;
    uint32_t u = a.u;
    uint32_t r = (u + 0x7fffu + ((u >> 16) & 1u)) >> 16;   // RNE
    return (unsigned short)r;
}

__device__ __forceinline__ float sigm(float v) { return 1.0f / (1.0f + __expf(-v)); }

// ---------------------------------------------------------------------------
// Kernel 1: transpose x [B][D][T] f32  ->  xt [T][B][D] bf16
// ---------------------------------------------------------------------------
__global__ void xt_kernel(const float* __restrict__ x, unsigned short* __restrict__ xt) {
    __shared__ unsigned short tile[128][66];
    const int b  = blockIdx.x >> 3;
    const int t0 = (blockIdx.x & 7) << 6;
    const int tid = threadIdx.x;
    const int j  = tid & 63;
    const int dq = tid >> 6;

#pragma unroll
    for (int it = 0; it < 32; ++it) {
        int d = it * 4 + dq;
        tile[d][j] = f2bf(x[(size_t)(b * D_ + d) * T_ + t0 + j]);
    }
    __syncthreads();

    uint32_t* xt32 = (uint32_t*)xt;
#pragma unroll
    for (int it = 0; it < 16; ++it) {
        int tl = it * 4 + dq;
        int dp = j;
        uint32_t lo = tile[2 * dp][tl];
        uint32_t hi = tile[2 * dp + 1][tl];
        xt32[(size_t)((t0 + tl) * B_ + b) * (D_ / 2) + dp] = lo | (hi << 16);
    }
}

// ---------------------------------------------------------------------------
// Kernel 2: persistent LSTM recurrence — clique-of-4, zero-LDS, zero-barrier.
// 64 blocks = 16 batch-chunks (bc) x 4 unit-quarters (hcq); 4 waves/block.
// Wave owns 16 units x 16 rows x ALL 4 gates: 48 mfma_16x16x32_bf16 per step,
// all 48 B-fragments (12 K-slices x 4 gates) resident in 192 VGPRs.
// C/D layout puts all 4 gates' pre-activations for (row quad*4+r, unit mrow)
// in ONE lane -> activation entirely in-register: no pre_s, no h_s, no x_s,
// no __syncthreads anywhere in the loop.
// h exchange: per-step slot in hbuf (bf16 [T][B][H], 0xFF sentinel memset).
// Producers fire-and-forget relaxed agent u32 stores (2 packed bf16; a data
// u32 can never be 0xFFFFFFFF). Consumers load their MFMA A-fragments
// DIRECTLY from hbuf with sc1 dwordx4 loads, poll per-u32 until no sentinel.
// Only 4 producer blocks per clique -> minimal straggler skew.
// ---------------------------------------------------------------------------
#define ISSUE_H(base_)                                                                             \
    do {                                                                                           \
        const unsigned short* hsrc_ = (base_);                                                     \
        asm volatile("global_load_dwordx4 %0, %1, off sc1"            : "=v"(hv[0]) : "v"(hsrc_)); \
        asm volatile("global_load_dwordx4 %0, %1, off offset:64 sc1"  : "=v"(hv[1]) : "v"(hsrc_)); \
        asm volatile("global_load_dwordx4 %0, %1, off offset:128 sc1" : "=v"(hv[2]) : "v"(hsrc_)); \
        asm volatile("global_load_dwordx4 %0, %1, off offset:192 sc1" : "=v"(hv[3]) : "v"(hsrc_)); \
        asm volatile("global_load_dwordx4 %0, %1, off offset:256 sc1" : "=v"(hv[4]) : "v"(hsrc_)); \
        asm volatile("global_load_dwordx4 %0, %1, off offset:320 sc1" : "=v"(hv[5]) : "v"(hsrc_)); \
        asm volatile("global_load_dwordx4 %0, %1, off offset:384 sc1" : "=v"(hv[6]) : "v"(hsrc_)); \
        asm volatile("global_load_dwordx4 %0, %1, off offset:448 sc1" : "=v"(hv[7]) : "v"(hsrc_)); \
    } while (0)

__global__ void __launch_bounds__(256, 1) lstm_kernel(
    const float* __restrict__ Wgx, const float* __restrict__ Wix,
    const float* __restrict__ Wfx, const float* __restrict__ Wox,
    const float* __restrict__ Wgh, const float* __restrict__ Wih,
    const float* __restrict__ Wfh, const float* __restrict__ Woh,
    const float* __restrict__ bg,  const float* __restrict__ bi,
    const float* __restrict__ bf2, const float* __restrict__ bo,
    const unsigned short* __restrict__ xt,
    unsigned short* __restrict__ hbuf,
    float* __restrict__ hfin)
{
    const int tid  = threadIdx.x;
    const int bc   = blockIdx.x >> 2;      // 16 batch chunks of 16 rows
    const int hcq  = blockIdx.x & 3;       // 4 unit quarters of 64 units
    const int wave = tid >> 6;
    const int lane = tid & 63;
    const int mrow = lane & 15;
    const int quad = lane >> 4;
    const int u    = hcq * 64 + wave * 16 + mrow;   // this lane's output unit

    const float* WxA[4] = {Wgx, Wix, Wfx, Wox};
    const float* WhA[4] = {Wgh, Wih, Wfh, Woh};

    // ---- one-time: gather all 48 B-fragments into registers -------------
    // B-frag layout (verified against working kernel): lane holds
    // B[k = quad*8 + j][n = mrow] of each 32-wide K-slice.
    s16x8 wf[4][12];
#pragma unroll
    for (int g = 0; g < 4; ++g) {
#pragma unroll
        for (int ks = 0; ks < 12; ++ks) {
            const float* src = (ks < 4)
                ? (WxA[g] + (size_t)(ks * 32 + quad * 8) * H_ + u)
                : (WhA[g] + (size_t)((ks - 4) * 32 + quad * 8) * H_ + u);
            s16x8 v;
#pragma unroll
            for (int j = 0; j < 8; ++j)
                v[j] = (short)f2bf(src[(size_t)j * H_]);
            wf[g][ks] = v;
        }
    }

    const float bs0 = bg[u], bs1 = bi[u], bs2 = bf2[u], bs3 = bo[u];

    float cst[4] = {0.f, 0.f, 0.f, 0.f};
    float hst[4] = {0.f, 0.f, 0.f, 0.f};

    u32x4 hv[8] = {};
    u32x4 xa[4];

    // x A-fragments for t=0 (plain cached loads; A[row=mrow][k=quad*8+j])
    {
        const unsigned short* p = xt + (size_t)(bc * 16 + mrow) * D_ + quad * 8;
        xa[0] = *(const u32x4*)(p);      xa[1] = *(const u32x4*)(p + 32);
        xa[2] = *(const u32x4*)(p + 64); xa[3] = *(const u32x4*)(p + 96);
    }

    for (int t = 0; t < T_; ++t) {
        f32x4 acc[4];
#pragma unroll
        for (int g = 0; g < 4; ++g) acc[g] = (f32x4){0.f, 0.f, 0.f, 0.f};

        // ---- x-part MFMAs: no h dependency, run while h loads fly -------
#pragma unroll
        for (int ks = 0; ks < 4; ++ks) {
            s16x8 A = __builtin_bit_cast(s16x8, xa[ks]);
#pragma unroll
            for (int g = 0; g < 4; ++g)
                acc[g] = __builtin_amdgcn_mfma_f32_16x16x32_bf16(A, wf[g][ks], acc[g], 0, 0, 0);
        }
        __builtin_amdgcn_sched_barrier(0);   // keep x-MFMAs above the poll

        if (t > 0) {
            // ---- poll: in-flight sc1 loads ARE the data; retry on sentinel
            for (;;) {
                asm volatile("s_waitcnt vmcnt(0)" ::: "memory");
                __builtin_amdgcn_sched_barrier(0);
                uint32_t m = 0;
#pragma unroll
                for (int i = 0; i < 8; ++i) {
                    m = m > hv[i].x ? m : hv[i].x;
                    m = m > hv[i].y ? m : hv[i].y;
                    m = m > hv[i].z ? m : hv[i].z;
                    m = m > hv[i].w ? m : hv[i].w;
                }
                if (__all(m != S32)) break;   // max==S32 iff any word is sentinel
                __builtin_amdgcn_s_sleep(1);
                ISSUE_H(hbuf + ((size_t)(t - 1) * B_ + bc * 16 + mrow) * H_ + quad * 8);
            }
            // ---- h-part MFMAs straight from the loaded fragments --------
#pragma unroll
            for (int ks = 0; ks < 8; ++ks) {
                s16x8 A = __builtin_bit_cast(s16x8, hv[ks]);
#pragma unroll
                for (int g = 0; g < 4; ++g)
                    acc[g] = __builtin_amdgcn_mfma_f32_16x16x32_bf16(A, wf[g][4 + ks], acc[g], 0, 0, 0);
            }
        }

        // prefetch x fragments for t+1 (cached; completes during activation)
        if (t + 1 < T_) {
            const unsigned short* p = xt + ((size_t)(t + 1) * B_ + bc * 16 + mrow) * D_ + quad * 8;
            xa[0] = *(const u32x4*)(p);      xa[1] = *(const u32x4*)(p + 32);
            xa[2] = *(const u32x4*)(p + 64); xa[3] = *(const u32x4*)(p + 96);
        }

        // ---- activation fully in-register (rows quad*4+r, unit mrow) ----
#pragma unroll
        for (int r = 0; r < 4; ++r) {
            float pg = acc[0][r] + bs0;
            float pi = acc[1][r] + bs1;
            float pf = acc[2][r] + bs2;
            float po = acc[3][r] + bs3;
            float gg = 2.0f * sigm(2.0f * pg) - 1.0f;   // tanh
            float ii = sigm(pi), ff = sigm(pf), oo = sigm(po);
            cst[r] = gg * ii + cst[r] * ff;
            hst[r] = (2.0f * sigm(2.0f * cst[r]) - 1.0f) * oo;
        }

        // ---- publish h: pack unit pairs, relaxed agent u32 stores -------
        unsigned short* drow = hbuf + ((size_t)t * B_ + bc * 16 + quad * 4) * H_ + u;
#pragma unroll
        for (int r = 0; r < 4; ++r) {
            uint32_t hb = f2bf(hst[r]);
            uint32_t p2 = hb | ((uint32_t)__shfl_down((int)hb, 1, 64) << 16);
            if ((mrow & 1) == 0)
                __hip_atomic_store((uint32_t*)(drow + (size_t)r * H_), p2,
                                   __ATOMIC_RELAXED, __HIP_MEMORY_SCOPE_AGENT);
        }

        // ---- early-issue next step's h A-fragment loads ------------------
        if (t + 1 < T_)
            ISSUE_H(hbuf + ((size_t)t * B_ + bc * 16 + mrow) * H_ + quad * 8);
    }

#pragma unroll
    for (int r = 0; r < 4; ++r)
        hfin[(size_t)(bc * 16 + quad * 4 + r) * H_ + u] = hst[r];
}

// ---------------------------------------------------------------------------
// Kernel 3: out = h_final @ W_ph + b_p
// ---------------------------------------------------------------------------
__global__ void proj_kernel(const float* __restrict__ hfin, const float* __restrict__ Wph,
                            const float* __restrict__ bp, float* __restrict__ out) {
    int gid = blockIdx.x * 256 + threadIdx.x;
    if (gid >= B_ * C_) return;
    int b = gid / C_, cc = gid % C_;
    float acc = bp[cc];
#pragma unroll 8
    for (int u = 0; u < H_; ++u)
        acc += hfin[(size_t)b * H_ + u] * Wph[(size_t)u * C_ + cc];
    out[gid] = acc;
}

// ---------------------------------------------------------------------------
extern "C" void kernel_launch(void* const* d_in, const int* in_sizes, int n_in,
                              void* d_out, int out_size, void* d_ws, size_t ws_size,
                              hipStream_t stream) {
    const float* x   = (const float*)d_in[0];
    const float* Wgx = (const float*)d_in[1];
    const float* Wix = (const float*)d_in[2];
    const float* Wfx = (const float*)d_in[3];
    const float* Wox = (const float*)d_in[4];
    const float* Wgh = (const float*)d_in[5];
    const float* Wih = (const float*)d_in[6];
    const float* Wfh = (const float*)d_in[7];
    const float* Woh = (const float*)d_in[8];
    const float* bg  = (const float*)d_in[9];
    const float* bi  = (const float*)d_in[10];
    const float* bf2 = (const float*)d_in[11];
    const float* bo  = (const float*)d_in[12];
    const float* Wph = (const float*)d_in[13];
    const float* bp  = (const float*)d_in[14];

    const size_t hbuf_bytes = (size_t)T_ * B_ * H_ * 2;   // 64 MB bf16 [T][B][H]

    char* ws = (char*)d_ws;
    unsigned short* hbuf = (unsigned short*)ws;
    float*          hfin = (float*)(ws + hbuf_bytes);
    unsigned short* xt   = (unsigned short*)(ws + hbuf_bytes + (size_t)B_ * H_ * sizeof(float));

    // sentinel-fill the h exchange buffer (bf16 NaN pattern 0xFFFF)
    hipMemsetAsync(hbuf, 0xFF, hbuf_bytes, stream);

    xt_kernel<<<B_ * (T_ / 64), 256, 0, stream>>>(x, xt);

    lstm_kernel<<<64, 256, 0, stream>>>(Wgx, Wix, Wfx, Wox, Wgh, Wih, Wfh, Woh,
                                        bg, bi, bf2, bo, xt, hbuf, hfin);

    proj_kernel<<<(B_ * C_ + 255) / 256, 256, 0, stream>>>(hfin, Wph, bp, (float*)d_out);
}

// Round 4
// 2219.675 us; speedup vs baseline: 2.3639x; 1.0051x over previous
//
#include <hip/hip_runtime.h>
#include <hip/hip_bf16.h>
#include <cstdint>

#define B_ 256
#define D_ 128
#define T_ 512
#define H_ 256
#define C_ 10
#define S32 0xFFFFFFFFu

using f32x4 = __attribute__((ext_vector_type(4))) float;
using s16x8 = __attribute__((ext_vector_type(8))) short;
using u32x4 = __attribute__((ext_vector_type(4))) unsigned int;

__device__ __forceinline__ unsigned short f2bf(float f) {
    union { float f; uint32_t u; } a; a.f = f;
    uint32_t u = a.u;
    uint32_t r = (u + 0x7fffu + ((u >> 16) & 1u)) >> 16;   // RNE
    return (unsigned short)r;
}

__device__ __forceinline__ float sigm(float v) { return 1.0f / (1.0f + __expf(-v)); }

// ---------------------------------------------------------------------------
// Kernel 1: transpose x [B][D][T] f32  ->  xt [T][B][D] bf16
// ---------------------------------------------------------------------------
__global__ void xt_kernel(const float* __restrict__ x, unsigned short* __restrict__ xt) {
    __shared__ unsigned short tile[128][66];
    const int b  = blockIdx.x >> 3;
    const int t0 = (blockIdx.x & 7) << 6;
    const int tid = threadIdx.x;
    const int j  = tid & 63;
    const int dq = tid >> 6;

#pragma unroll
    for (int it = 0; it < 32; ++it) {
        int d = it * 4 + dq;
        tile[d][j] = f2bf(x[(size_t)(b * D_ + d) * T_ + t0 + j]);
    }
    __syncthreads();

    uint32_t* xt32 = (uint32_t*)xt;
#pragma unroll
    for (int it = 0; it < 16; ++it) {
        int tl = it * 4 + dq;
        int dp = j;
        uint32_t lo = tile[2 * dp][tl];
        uint32_t hi = tile[2 * dp + 1][tl];
        xt32[(size_t)((t0 + tl) * B_ + b) * (D_ / 2) + dp] = lo | (hi << 16);
    }
}

// ---------------------------------------------------------------------------
// Kernel 2: persistent LSTM recurrence — clique-of-4, zero-LDS, zero-barrier,
// HAND-COUNTED vmcnt discipline (all loop vmem via asm, fixed issue order
// xa -> stores -> hv each step):
//   top of step:      s_waitcnt vmcnt(12)  -> xa(t) ready (stores+hv younger)
//   after next-xa:    s_waitcnt vmcnt(4)   -> hv(slot t-1) ready, store acks
//   retry path only:  s_waitcnt vmcnt(0)
// So x-MFMAs overlap the in-flight h loads, and the early-issued h loads are
// never drained prematurely (round-3 defect #2).
// h stores re-packed via shfl into 4 u64 stores/wave (16 lanes x 8B = 32B
// contiguous per row) instead of 128 scattered u32s (round-3 defect #1).
// ---------------------------------------------------------------------------
#define ISSUE_H(base_)                                                                             \
    do {                                                                                           \
        const unsigned short* hsrc_ = (base_);                                                     \
        asm volatile("global_load_dwordx4 %0, %1, off sc1"            : "=v"(hv[0]) : "v"(hsrc_)); \
        asm volatile("global_load_dwordx4 %0, %1, off offset:64 sc1"  : "=v"(hv[1]) : "v"(hsrc_)); \
        asm volatile("global_load_dwordx4 %0, %1, off offset:128 sc1" : "=v"(hv[2]) : "v"(hsrc_)); \
        asm volatile("global_load_dwordx4 %0, %1, off offset:192 sc1" : "=v"(hv[3]) : "v"(hsrc_)); \
        asm volatile("global_load_dwordx4 %0, %1, off offset:256 sc1" : "=v"(hv[4]) : "v"(hsrc_)); \
        asm volatile("global_load_dwordx4 %0, %1, off offset:320 sc1" : "=v"(hv[5]) : "v"(hsrc_)); \
        asm volatile("global_load_dwordx4 %0, %1, off offset:384 sc1" : "=v"(hv[6]) : "v"(hsrc_)); \
        asm volatile("global_load_dwordx4 %0, %1, off offset:448 sc1" : "=v"(hv[7]) : "v"(hsrc_)); \
    } while (0)

#define ISSUE_XA(base_)                                                                           \
    do {                                                                                          \
        const unsigned short* xsrc_ = (base_);                                                    \
        asm volatile("global_load_dwordx4 %0, %1, off"            : "=v"(xa[0]) : "v"(xsrc_));    \
        asm volatile("global_load_dwordx4 %0, %1, off offset:64"  : "=v"(xa[1]) : "v"(xsrc_));    \
        asm volatile("global_load_dwordx4 %0, %1, off offset:128" : "=v"(xa[2]) : "v"(xsrc_));    \
        asm volatile("global_load_dwordx4 %0, %1, off offset:192" : "=v"(xa[3]) : "v"(xsrc_));    \
    } while (0)

__global__ void __launch_bounds__(256, 1) lstm_kernel(
    const float* __restrict__ Wgx, const float* __restrict__ Wix,
    const float* __restrict__ Wfx, const float* __restrict__ Wox,
    const float* __restrict__ Wgh, const float* __restrict__ Wih,
    const float* __restrict__ Wfh, const float* __restrict__ Woh,
    const float* __restrict__ bg,  const float* __restrict__ bi,
    const float* __restrict__ bf2, const float* __restrict__ bo,
    const unsigned short* __restrict__ xt,
    unsigned short* __restrict__ hbuf,
    float* __restrict__ hfin)
{
    const int tid  = threadIdx.x;
    const int bc   = blockIdx.x >> 2;      // 16 batch chunks of 16 rows
    const int hcq  = blockIdx.x & 3;       // 4 unit quarters of 64 units
    const int wave = tid >> 6;
    const int lane = tid & 63;
    const int mrow = lane & 15;
    const int quad = lane >> 4;
    const int u    = hcq * 64 + wave * 16 + mrow;   // this lane's output unit

    const float* WxA[4] = {Wgx, Wix, Wfx, Wox};
    const float* WhA[4] = {Wgh, Wih, Wfh, Woh};

    // ---- one-time: gather all 48 B-fragments into registers -------------
    s16x8 wf[4][12];
#pragma unroll
    for (int g = 0; g < 4; ++g) {
#pragma unroll
        for (int ks = 0; ks < 12; ++ks) {
            const float* src = (ks < 4)
                ? (WxA[g] + (size_t)(ks * 32 + quad * 8) * H_ + u)
                : (WhA[g] + (size_t)((ks - 4) * 32 + quad * 8) * H_ + u);
            s16x8 v;
#pragma unroll
            for (int j = 0; j < 8; ++j)
                v[j] = (short)f2bf(src[(size_t)j * H_]);
            wf[g][ks] = v;
        }
    }

    const float bs0 = bg[u], bs1 = bi[u], bs2 = bf2[u], bs3 = bo[u];

    float cst[4] = {0.f, 0.f, 0.f, 0.f};
    float hst[4] = {0.f, 0.f, 0.f, 0.f};

    u32x4 hv[8] = {};
    u32x4 xa[4];

    // lane's A-fragment source rows (shared by all 4 waves of the block)
    const size_t arow = (size_t)(bc * 16 + mrow);

    // =====================  t = 0 prologue  ==============================
    ISSUE_XA(xt + (size_t)(0 * B_ + arow) * D_ + quad * 8);
    asm volatile("s_waitcnt vmcnt(0)" ::: "memory");
    __builtin_amdgcn_sched_barrier(0);

    f32x4 acc[4];
#pragma unroll
    for (int g = 0; g < 4; ++g) acc[g] = (f32x4){0.f, 0.f, 0.f, 0.f};
#pragma unroll
    for (int ks = 0; ks < 4; ++ks) {
        s16x8 A = __builtin_bit_cast(s16x8, xa[ks]);
#pragma unroll
        for (int g = 0; g < 4; ++g)
            acc[g] = __builtin_amdgcn_mfma_f32_16x16x32_bf16(A, wf[g][ks], acc[g], 0, 0, 0);
    }
    __builtin_amdgcn_sched_barrier(0);
    ISSUE_XA(xt + (size_t)(1 * B_ + arow) * D_ + quad * 8);   // xa(1)
    __builtin_amdgcn_sched_barrier(0);

#pragma unroll
    for (int r = 0; r < 4; ++r) {
        float pg = acc[0][r] + bs0;
        float pi = acc[1][r] + bs1;
        float pf = acc[2][r] + bs2;
        float po = acc[3][r] + bs3;
        float gg = 2.0f * sigm(2.0f * pg) - 1.0f;
        float ii = sigm(pi), ff = sigm(pf), oo = sigm(po);
        cst[r] = gg * ii + cst[r] * ff;
        hst[r] = (2.0f * sigm(2.0f * cst[r]) - 1.0f) * oo;
    }
    // pack + store slot 0 (4 u64 stores/wave, lanes mrow%4==0)
    {
#pragma unroll
        for (int r = 0; r < 4; ++r) {
            uint32_t hb = f2bf(hst[r]);
            uint32_t p2 = hb | ((uint32_t)__shfl_down((int)hb, 1, 64) << 16);
            uint32_t q2 = (uint32_t)__shfl_down((int)p2, 2, 64);
            if ((mrow & 3) == 0) {
                uint64_t val = ((uint64_t)q2 << 32) | (uint64_t)p2;
                uint64_t* dst = (uint64_t*)(hbuf +
                    ((size_t)0 * B_ + bc * 16 + quad * 4 + r) * H_ + u);
                __hip_atomic_store(dst, val, __ATOMIC_RELAXED, __HIP_MEMORY_SCOPE_AGENT);
            }
        }
    }
    __builtin_amdgcn_sched_barrier(0);
    ISSUE_H(hbuf + ((size_t)0 * B_ + arow) * H_ + quad * 8);  // hv(slot 0)
    __builtin_amdgcn_sched_barrier(0);

    // =====================  steady loop t = 1..511  ======================
    for (int t = 1; t < T_; ++t) {
        // xa(t) ready: younger = stores(4) + hv(8) = 12
        asm volatile("s_waitcnt vmcnt(12)" ::: "memory");
        __builtin_amdgcn_sched_barrier(0);

#pragma unroll
        for (int g = 0; g < 4; ++g) acc[g] = (f32x4){0.f, 0.f, 0.f, 0.f};
#pragma unroll
        for (int ks = 0; ks < 4; ++ks) {
            s16x8 A = __builtin_bit_cast(s16x8, xa[ks]);
#pragma unroll
            for (int g = 0; g < 4; ++g)
                acc[g] = __builtin_amdgcn_mfma_f32_16x16x32_bf16(A, wf[g][ks], acc[g], 0, 0, 0);
        }
        __builtin_amdgcn_sched_barrier(0);

        // issue xa(t+1) (clamped at the end to keep vmem counts uniform)
        {
            int tn = (t + 1 < T_) ? (t + 1) : (T_ - 1);
            ISSUE_XA(xt + ((size_t)tn * B_ + arow) * D_ + quad * 8);
        }
        __builtin_amdgcn_sched_barrier(0);

        // hv(slot t-1) ready (and stores(t-1) acked): younger = xa(4)
        asm volatile("s_waitcnt vmcnt(4)" ::: "memory");
        __builtin_amdgcn_sched_barrier(0);

        // sentinel check; retry path re-issues and fully drains
        const unsigned short* hsrc = hbuf + ((size_t)(t - 1) * B_ + arow) * H_ + quad * 8;
        for (;;) {
            uint32_t m = 0;
#pragma unroll
            for (int i = 0; i < 8; ++i) {
                m = m > hv[i].x ? m : hv[i].x;
                m = m > hv[i].y ? m : hv[i].y;
                m = m > hv[i].z ? m : hv[i].z;
                m = m > hv[i].w ? m : hv[i].w;
            }
            if (__all(m != S32)) break;
            __builtin_amdgcn_s_sleep(1);
            ISSUE_H(hsrc);
            asm volatile("s_waitcnt vmcnt(0)" ::: "memory");
            __builtin_amdgcn_sched_barrier(0);
        }

        // h-part MFMAs straight from the loaded fragments
#pragma unroll
        for (int ks = 0; ks < 8; ++ks) {
            s16x8 A = __builtin_bit_cast(s16x8, hv[ks]);
#pragma unroll
            for (int g = 0; g < 4; ++g)
                acc[g] = __builtin_amdgcn_mfma_f32_16x16x32_bf16(A, wf[g][4 + ks], acc[g], 0, 0, 0);
        }

        // activation fully in-register (rows quad*4+r, unit mrow)
#pragma unroll
        for (int r = 0; r < 4; ++r) {
            float pg = acc[0][r] + bs0;
            float pi = acc[1][r] + bs1;
            float pf = acc[2][r] + bs2;
            float po = acc[3][r] + bs3;
            float gg = 2.0f * sigm(2.0f * pg) - 1.0f;
            float ii = sigm(pi), ff = sigm(pf), oo = sigm(po);
            cst[r] = gg * ii + cst[r] * ff;
            hst[r] = (2.0f * sigm(2.0f * cst[r]) - 1.0f) * oo;
        }

        // pack + publish h(t): 4 u64 coalesced agent stores per wave
        __builtin_amdgcn_sched_barrier(0);
#pragma unroll
        for (int r = 0; r < 4; ++r) {
            uint32_t hb = f2bf(hst[r]);
            uint32_t p2 = hb | ((uint32_t)__shfl_down((int)hb, 1, 64) << 16);
            uint32_t q2 = (uint32_t)__shfl_down((int)p2, 2, 64);
            if ((mrow & 3) == 0) {
                uint64_t val = ((uint64_t)q2 << 32) | (uint64_t)p2;
                uint64_t* dst = (uint64_t*)(hbuf +
                    ((size_t)t * B_ + bc * 16 + quad * 4 + r) * H_ + u);
                __hip_atomic_store(dst, val, __ATOMIC_RELAXED, __HIP_MEMORY_SCOPE_AGENT);
            }
        }
        __builtin_amdgcn_sched_barrier(0);

        // early-issue next step's h A-fragment loads (slot t)
        ISSUE_H(hbuf + ((size_t)t * B_ + arow) * H_ + quad * 8);
        __builtin_amdgcn_sched_barrier(0);
    }

#pragma unroll
    for (int r = 0; r < 4; ++r)
        hfin[(size_t)(bc * 16 + quad * 4 + r) * H_ + u] = hst[r];
}

// ---------------------------------------------------------------------------
// Kernel 3: out = h_final @ W_ph + b_p
// ---------------------------------------------------------------------------
__global__ void proj_kernel(const float* __restrict__ hfin, const float* __restrict__ Wph,
                            const float* __restrict__ bp, float* __restrict__ out) {
    int gid = blockIdx.x * 256 + threadIdx.x;
    if (gid >= B_ * C_) return;
    int b = gid / C_, cc = gid % C_;
    float acc = bp[cc];
#pragma unroll 8
    for (int u = 0; u < H_; ++u)
        acc += hfin[(size_t)b * H_ + u] * Wph[(size_t)u * C_ + cc];
    out[gid] = acc;
}

// ---------------------------------------------------------------------------
extern "C" void kernel_launch(void* const* d_in, const int* in_sizes, int n_in,
                              void* d_out, int out_size, void* d_ws, size_t ws_size,
                              hipStream_t stream) {
    const float* x   = (const float*)d_in[0];
    const float* Wgx = (const float*)d_in[1];
    const float* Wix = (const float*)d_in[2];
    const float* Wfx = (const float*)d_in[3];
    const float* Wox = (const float*)d_in[4];
    const float* Wgh = (const float*)d_in[5];
    const float* Wih = (const float*)d_in[6];
    const float* Wfh = (const float*)d_in[7];
    const float* Woh = (const float*)d_in[8];
    const float* bg  = (const float*)d_in[9];
    const float* bi  = (const float*)d_in[10];
    const float* bf2 = (const float*)d_in[11];
    const float* bo  = (const float*)d_in[12];
    const float* Wph = (const float*)d_in[13];
    const float* bp  = (const float*)d_in[14];

    const size_t hbuf_bytes = (size_t)T_ * B_ * H_ * 2;   // 64 MB bf16 [T][B][H]

    char* ws = (char*)d_ws;
    unsigned short* hbuf = (unsigned short*)ws;
    float*          hfin = (float*)(ws + hbuf_bytes);
    unsigned short* xt   = (unsigned short*)(ws + hbuf_bytes + (size_t)B_ * H_ * sizeof(float));

    // sentinel-fill the h exchange buffer (bf16 NaN pattern 0xFFFF)
    hipMemsetAsync(hbuf, 0xFF, hbuf_bytes, stream);

    xt_kernel<<<B_ * (T_ / 64), 256, 0, stream>>>(x, xt);

    lstm_kernel<<<64, 256, 0, stream>>>(Wgx, Wix, Wfx, Wox, Wgh, Wih, Wfh, Woh,
                                        bg, bi, bf2, bo, xt, hbuf, hfin);

    proj_kernel<<<(B_ * C_ + 255) / 256, 256, 0, stream>>>(hfin, Wph, bp, (float*)d_out);
}